// Round 6
// baseline (1178.126 us; speedup 1.0000x reference)
//
#include <hip/hip_runtime.h>
#include <hip/hip_bf16.h>
#include <math.h>

#define IGNORE_INDEX (-100)

constexpr int N = 8192;
constexpr int D = 1024;
constexpr int V = 50257;

constexpr int BM = 128;
constexpr int BN = 256;
constexpr int BK = 128;                  // one 16x16x128 MFMA K-depth per ks
constexpr int NC = 16;                   // V-chunks (grid.x)
constexpr int SUBT = (V + BN - 1) / BN;  // 197 column tiles

constexpr float LOG2E = 1.44269504088896340736f;
constexpr float LN2 = 0.69314718055994530942f;

typedef __attribute__((ext_vector_type(8))) int int8v;
typedef __attribute__((ext_vector_type(4))) float floatx4;

union Frag8 {  // build int8v from two 16B loads without element movs
  int4 p[2];
  int8v v;
};

__device__ __forceinline__ void gload_lds16(const void* g, void* l) {
  __builtin_amdgcn_global_load_lds(
      (const __attribute__((address_space(1))) void*)g,
      (__attribute__((address_space(3))) void*)l, 16, 0, 0);
}

__device__ __forceinline__ float fexp2(float x) {
#if __has_builtin(__builtin_amdgcn_exp2f)
  return __builtin_amdgcn_exp2f(x);
#else
  return exp2f(x);
#endif
}

// ---------------- prep: fp8(e4m3, OCP) casts + exact fp32 target dot --------
constexpr int E8 = N * D / 8;
constexpr int C8 = V * D / 8;
constexpr int EB = E8 / 256;          // 4096 blocks
constexpr int CB = (C8 + 255) / 256;  // 25129 blocks
constexpr int TGT_BLOCKS = N / 4;     // 2048 blocks

__device__ __forceinline__ unsigned int pk4_fp8(float a, float b, float c,
                                                float d) {
  int p = __builtin_amdgcn_cvt_pk_fp8_f32(a, b, 0, false);
  p = __builtin_amdgcn_cvt_pk_fp8_f32(c, d, p, true);
  return (unsigned int)p;
}

__global__ void prep_kernel(const float* __restrict__ e,
                            const float* __restrict__ c,
                            const int* __restrict__ t,
                            unsigned int* __restrict__ e8,
                            unsigned int* __restrict__ c8,
                            float* __restrict__ tgt) {
  const int b = blockIdx.x;
  if (b < EB) {
    const int idx = b * 256 + threadIdx.x;
    const float4 v0 = ((const float4*)e)[idx * 2];
    const float4 v1 = ((const float4*)e)[idx * 2 + 1];
    uint2 o;
    o.x = pk4_fp8(v0.x * LOG2E, v0.y * LOG2E, v0.z * LOG2E, v0.w * LOG2E);
    o.y = pk4_fp8(v1.x * LOG2E, v1.y * LOG2E, v1.z * LOG2E, v1.w * LOG2E);
    ((uint2*)e8)[idx] = o;
  } else if (b < EB + CB) {
    const int idx = (b - EB) * 256 + threadIdx.x;
    if (idx < C8) {
      const float4 v0 = ((const float4*)c)[idx * 2];
      const float4 v1 = ((const float4*)c)[idx * 2 + 1];
      uint2 o;
      o.x = pk4_fp8(v0.x, v0.y, v0.z, v0.w);
      o.y = pk4_fp8(v1.x, v1.y, v1.z, v1.w);
      ((uint2*)c8)[idx] = o;
    }
  } else {
    const int row = (b - EB - CB) * 4 + (threadIdx.x >> 6);
    const int lane = threadIdx.x & 63;
    int tr = t[row];
    if (tr == IGNORE_INDEX) tr = 0;
    const float4* ev = (const float4*)(e + (size_t)row * D);
    const float4* cv = (const float4*)(c + (size_t)tr * D);
    float s = 0.f;
#pragma unroll
    for (int k = 0; k < 4; ++k) {
      float4 a = ev[lane + k * 64];
      float4 bb = cv[lane + k * 64];
      s += a.x * bb.x + a.y * bb.y + a.z * bb.z + a.w * bb.w;
    }
#pragma unroll
    for (int d = 1; d < 64; d <<= 1) s += __shfl_xor(s, d, 64);
    if (lane == 0) tgt[row] = s;
  }
}

// ---------------- fused fp8 GEMM + online logsumexp partials ----------------
// A = e_fp8 (log2e-scaled) [N][D], B = c_fp8 [V][D], K-major bytes.
// MFMA: 16x16x128 f8f6f4, fmt=fp8 both, scales = 1 (bytes 0x7F).
// B staged via global_load_lds into a DOUBLE-BUFFERED LDS (one barrier per ks;
// stage(ks+1) issued post-barrier so the next barrier's vmcnt(0) drain is
// overlapped by compute). A frags load direct from global (L2-hot, 32B/lane).
__global__ __launch_bounds__(256, 2) void gemm_lse_kernel(
    const unsigned char* __restrict__ A, const unsigned char* __restrict__ B,
    float* __restrict__ m_part, float* __restrict__ s_part) {
  __shared__ char smB[2][BN * BK];  // 2 x 32 KB (static LDS at the 64KB cap)

  const int chunk = blockIdx.x;
  const int row0 = blockIdx.y * BM;
  const int tid = threadIdx.x;
  const int wave = tid >> 6;
  const int lane = tid & 63;
  const int wr = wave >> 1;  // row half (64 rows)
  const int wc = wave & 1;   // col half (128 cols)
  const int quad = lane >> 4;
  const int l16 = lane & 15;

  // B staging: lane's LDS slot fixed (chunk base + lane*16); source vec
  // chosen so physical vec pv holds logical vec pv ^ (row&7).
  const int lrow = lane >> 3;
  const int lvec_st = (lane & 7) ^ lrow;
  const int stage_off = wave * 8 * 1024 + lane * 16;

  // A fragment base: row = row0 + wr*64 + i*16 + l16, k = quad*32 + 0..31
  const unsigned char* abase =
      A + (size_t)(row0 + wr * 64 + l16) * D + quad * 32;

  float rm[16], rs[16];
#pragma unroll
  for (int x = 0; x < 16; ++x) { rm[x] = -1e30f; rs[x] = 0.0f; }

  const int nsub = (SUBT - chunk + NC - 1) / NC;  // round-robin col tiles
  const int it_total = nsub * 8;

  // preamble: stage (si=0, ks=0) into buffer 0
  {
    const int col0 = chunk * BN;
#pragma unroll
    for (int cc = 0; cc < 8; ++cc) {
      const int ch = wave * 8 + cc;
      int brow = col0 + ch * 8 + lrow;
      if (brow >= V) brow = V - 1;
      gload_lds16(B + (size_t)brow * D + lvec_st * 16,
                  smB[0] + ch * 1024 + lane * 16);
    }
  }

  floatx4 acc[4][8];
  for (int it = 0; it < it_total; ++it) {
    const int si = it >> 3;
    const int ks = it & 7;
    const int col0 = (chunk + si * NC) * BN;
    if (ks == 0) {
#pragma unroll
      for (int i = 0; i < 4; ++i)
#pragma unroll
        for (int j = 0; j < 8; ++j) acc[i][j] = floatx4{0.f, 0.f, 0.f, 0.f};
    }
    __syncthreads();  // drains stage(it) — it flew during compute(it-1)

    // stage(it+1) into the other buffer: overlapped with compute below
    const int it1 = it + 1;
    if (it1 < it_total) {
      const int col1 = (chunk + (it1 >> 3) * NC) * BN;
      const size_t kb1 = (size_t)((it1 & 7) * BK);
      char* dst = smB[it1 & 1] + stage_off;
#pragma unroll
      for (int cc = 0; cc < 8; ++cc) {
        int brow = col1 + (wave * 8 + cc) * 8 + lrow;
        if (brow >= V) brow = V - 1;
        gload_lds16(B + (size_t)brow * D + kb1 + lvec_st * 16,
                    dst + cc * 1024);
      }
    }

    // A frags: contiguous 32B per frag -> 2x dwordx4, no element movs
    int8v af[4];
#pragma unroll
    for (int i = 0; i < 4; ++i)
      af[i] = *(const int8v*)(abase + (size_t)i * 16 * D + ks * BK);

    const char* cur = smB[it & 1];
#pragma unroll
    for (int jh = 0; jh < 2; ++jh) {
      Frag8 bf[4];
#pragma unroll
      for (int jj = 0; jj < 4; ++jj) {
        const int cr = wc * 128 + (jh * 4 + jj) * 16 + l16;
        const char* base = cur + cr * 128;
        bf[jj].p[0] = *(const int4*)(base + (((quad * 2) ^ (cr & 7)) * 16));
        bf[jj].p[1] =
            *(const int4*)(base + (((quad * 2 + 1) ^ (cr & 7)) * 16));
      }
#pragma unroll
      for (int jj = 0; jj < 4; ++jj)
#pragma unroll
        for (int i = 0; i < 4; ++i)
          acc[i][jh * 4 + jj] =
              __builtin_amdgcn_mfma_scale_f32_16x16x128_f8f6f4(
                  af[i], bf[jj].v, acc[i][jh * 4 + jj], 0, 0,  // fp8/fp8
                  0, 0x7F7F7F7F, 0, 0x7F7F7F7F);  // scales = 2^0
    }  // jh

    if (ks == 7) {
      // per-tile per-thread online update. C layout: col=l16, row=quad*4+reg.
      const bool edge = (col0 + BN > V);
#pragma unroll
      for (int i = 0; i < 4; ++i) {
#pragma unroll
        for (int reg = 0; reg < 4; ++reg) {
          float v[8];
#pragma unroll
          for (int j = 0; j < 8; ++j) v[j] = acc[i][j][reg];
          if (edge) {
            const int cb = col0 + wc * 128 + l16;
#pragma unroll
            for (int j = 0; j < 8; ++j)
              if (cb + j * 16 >= V) v[j] = -INFINITY;
          }
          float mx = v[0];
#pragma unroll
          for (int j = 1; j < 8; ++j) mx = fmaxf(mx, v[j]);
          const int x = i * 4 + reg;
          const float nm = fmaxf(rm[x], mx);
          float s = rs[x] * fexp2(rm[x] - nm);
#pragma unroll
          for (int j = 0; j < 8; ++j) s += fexp2(v[j] - nm);
          rs[x] = s;
          rm[x] = nm;
        }
      }
    }
  }

  // once-per-kernel reduction: butterfly over the 16 lanes sharing each row.
  // red arrays alias smB (all LDS reads of the main loop are done).
  __syncthreads();
  float* red_m = (float*)&smB[0][0];  // [2][BM]
  float* red_s = (float*)&smB[0][2 * BM * 4];
#pragma unroll
  for (int x = 0; x < 16; ++x) {
    float m = rm[x], s = rs[x];
#pragma unroll
    for (int d = 1; d < 16; d <<= 1) {
      const float om = __shfl_xor(m, d, 64);
      const float os = __shfl_xor(s, d, 64);
      const float nm = fmaxf(m, om);
      s = s * fexp2(m - nm) + os * fexp2(om - nm);
      m = nm;
    }
    if (l16 == 0) {
      const int i = x >> 2, reg = x & 3;
      const int rloc = wr * 64 + i * 16 + quad * 4 + reg;
      red_m[wc * BM + rloc] = m;
      red_s[wc * BM + rloc] = s;
    }
  }
  __syncthreads();
  if (tid < BM) {  // merge the two column-half waves, write chunk partials
    const float m0 = red_m[tid], s0 = red_s[tid];
    const float m1 = red_m[BM + tid], s1 = red_s[BM + tid];
    const float tm = fmaxf(m0, m1);
    const float ts = s0 * fexp2(m0 - tm) + s1 * fexp2(m1 - tm);
    m_part[(size_t)chunk * N + row0 + tid] = tm;
    s_part[(size_t)chunk * N + row0 + tid] = ts;
  }
}

// ---------------- finalize: merge chunk partials, subtract target, mean -----
__global__ void finalize1_kernel(const float* __restrict__ m_part,
                                 const float* __restrict__ s_part,
                                 const float* __restrict__ tgt,
                                 const int* __restrict__ t,
                                 double* __restrict__ fin) {
  const int tid = threadIdx.x;
  const int row = blockIdx.x * 256 + tid;
  float M = -1e30f;
#pragma unroll
  for (int ch = 0; ch < NC; ++ch) M = fmaxf(M, m_part[ch * N + row]);
  float S = 0.f;
#pragma unroll
  for (int ch = 0; ch < NC; ++ch)
    S += s_part[ch * N + row] * fexp2(m_part[ch * N + row] - M);
  const float lse = LN2 * (M + log2f(S));  // back to natural-log space
  double nll = 0.0;
  double cnt = 0.0;
  if (t[row] != IGNORE_INDEX) {
    nll = (double)(lse - tgt[row]);
    cnt = 1.0;
  }
  __shared__ double sacc[256];
  __shared__ double scnt[256];
  sacc[tid] = nll;
  scnt[tid] = cnt;
  __syncthreads();
  for (int s = 128; s > 0; s >>= 1) {
    if (tid < s) {
      sacc[tid] += sacc[tid + s];
      scnt[tid] += scnt[tid + s];
    }
    __syncthreads();
  }
  if (tid == 0) {
    fin[blockIdx.x * 2] = sacc[0];
    fin[blockIdx.x * 2 + 1] = scnt[0];
  }
}

__global__ void finalize2_kernel(const double* __restrict__ fin,
                                 float* __restrict__ out) {
  const int tid = threadIdx.x;  // 64 threads, 32 active
  __shared__ double sa[64], sc[64];
  sa[tid] = (tid < 32) ? fin[tid * 2] : 0.0;
  sc[tid] = (tid < 32) ? fin[tid * 2 + 1] : 0.0;
  __syncthreads();
  for (int s = 32; s > 0; s >>= 1) {
    if (tid < s) {
      sa[tid] += sa[tid + s];
      sc[tid] += sc[tid + s];
    }
    __syncthreads();
  }
  if (tid == 0) out[0] = (float)(sa[0] / fmax(sc[0], 1.0));
}

extern "C" void kernel_launch(void* const* d_in, const int* in_sizes, int n_in,
                              void* d_out, int out_size, void* d_ws,
                              size_t ws_size, hipStream_t stream) {
  const float* e = (const float*)d_in[0];
  const float* c = (const float*)d_in[1];
  const int* t = (const int*)d_in[2];
  float* out = (float*)d_out;

  char* ws = (char*)d_ws;
  unsigned char* e8 = (unsigned char*)ws;  // 8 MB (log2e-scaled fp8)
  size_t off = (size_t)N * D;
  unsigned char* c8 = (unsigned char*)(ws + off);  // 51.5 MB
  off += (size_t)V * D;
  off = (off + 255) & ~(size_t)255;
  float* tgt = (float*)(ws + off);
  off += (size_t)N * 4;
  float* m_part = (float*)(ws + off);
  off += (size_t)NC * N * 4;
  float* s_part = (float*)(ws + off);
  off += (size_t)NC * N * 4;
  double* fin = (double*)(ws + off);
  off += 32 * 2 * sizeof(double);  // total ~61 MB of d_ws

  prep_kernel<<<EB + CB + TGT_BLOCKS, 256, 0, stream>>>(
      e, c, t, (unsigned int*)e8, (unsigned int*)c8, tgt);
  gemm_lse_kernel<<<dim3(NC, N / BM), 256, 0, stream>>>(e8, c8, m_part,
                                                        s_part);
  finalize1_kernel<<<32, 256, 0, stream>>>(m_part, s_part, tgt, t, fin);
  finalize2_kernel<<<1, 64, 0, stream>>>(fin, out);
}